// Round 9
// baseline (1270.974 us; speedup 1.0000x reference)
//
#include <hip/hip_runtime.h>
#include <stdint.h>

#define NNODES 50000
#define NEDGES 800000
#define NGRAPH 100
#define NCH32 (NEDGES / 32)    // 25000 32-edge chunks
#define NWAVES 4096            // 256 blocks x 16 waves

typedef _Float16 f16;
typedef __attribute__((ext_vector_type(8))) _Float16 half8;
typedef __attribute__((ext_vector_type(4))) _Float16 half4;
typedef __attribute__((ext_vector_type(4))) float floatx4;

// stage 128x128 fp32 row-major W[k][n] -> LDS WT[n][136 pad] fp16, float4 loads
__device__ __forceinline__ void stage_WT(const float* __restrict__ W, f16* WT,
                                         int tid, int nthr) {
    for (int idx = tid; idx < 128 * 32; idx += nthr) {
        int k = idx >> 5, n4 = (idx & 31) * 4;
        floatx4 v = *(const floatx4*)(W + k * 128 + n4);
        WT[(n4 + 0) * 136 + k] = (f16)v[0];
        WT[(n4 + 1) * 136 + k] = (f16)v[1];
        WT[(n4 + 2) * 136 + k] = (f16)v[2];
        WT[(n4 + 3) * 136 + k] = (f16)v[3];
    }
}

__device__ __forceinline__ float fast_tanh(float x) {
    x = fminf(fmaxf(x, -15.0f), 15.0f);
    float e2 = __expf(2.0f * x);
    return (e2 - 1.0f) * __builtin_amdgcn_rcpf(e2 + 1.0f);
}

__global__ void init_k(float* out, int osz, int* cnt) {
    int i = blockIdx.x * 256 + threadIdx.x;
    if (i < osz) out[i] = 0.0f;
    if (i < NNODES) cnt[i] = 0;
}

__global__ void hist_k(const int* __restrict__ dst, int* __restrict__ cnt) {
    int e = blockIdx.x * 256 + threadIdx.x;
    if (e < NEDGES) atomicAdd(&cnt[dst[e]], 1);
}

__global__ __launch_bounds__(1024) void scan1_k(const int* __restrict__ cnt,
                                                int* __restrict__ rowStart,
                                                int* __restrict__ blockSum) {
    __shared__ int buf[1024];
    int tid = threadIdx.x;
    int i = blockIdx.x * 1024 + tid;
    int v = (i < NNODES) ? cnt[i] : 0;
    buf[tid] = v;
    __syncthreads();
    for (int off = 1; off < 1024; off <<= 1) {
        int t = (tid >= off) ? buf[tid - off] : 0;
        __syncthreads();
        buf[tid] += t;
        __syncthreads();
    }
    if (i < NNODES) rowStart[i] = buf[tid] - v;
    if (tid == 1023) blockSum[blockIdx.x] = buf[1023];
}

__global__ void scan2_k(int* __restrict__ blockSum, int nb) {
    if (threadIdx.x == 0) {
        int run = 0;
        for (int b = 0; b < nb; ++b) { int s = blockSum[b]; blockSum[b] = run; run += s; }
    }
}

__global__ __launch_bounds__(1024) void scan3_k(int* __restrict__ rowStart,
                                                const int* __restrict__ blockSum,
                                                int* __restrict__ cnt) {
    int i = blockIdx.x * 1024 + threadIdx.x;
    if (i < NNODES) { rowStart[i] += blockSum[blockIdx.x]; cnt[i] = 0; }
    if (i == 0) rowStart[NNODES] = NEDGES;
}

__global__ void scatter_k(const int* __restrict__ src, const int* __restrict__ et,
                          const int* __restrict__ dst, const float* __restrict__ dist,
                          const int* __restrict__ rowStart, int* __restrict__ cnt,
                          uint4* __restrict__ packE) {
    int e = blockIdx.x * 256 + threadIdx.x;
    if (e >= NEDGES) return;
    int d = dst[e];
    int pos = rowStart[d] + atomicAdd(&cnt[d], 1);
    uint4 pk;
    pk.x = (unsigned)src[e];
    pk.y = (unsigned)et[e];
    pk.z = (unsigned)d;
    pk.w = __float_as_uint(dist[e]);
    packE[pos] = pk;
}

__global__ void gather_h(const int* __restrict__ nt, const float* __restrict__ emb,
                         float* __restrict__ h) {
    int i = blockIdx.x * 256 + threadIdx.x;
    int row = i >> 5, c4 = (i & 31) * 4;
    if (row < NNODES)
        *(floatx4*)(h + row * 128 + c4) = *(const floatx4*)(emb + nt[row] * 128 + c4);
}

// MODE 0: relu(X@W1+b1)@W2+b2 -> Out f16   MODE 2: X@W1+b1 -> Out f16
template <int MODE>
__global__ __launch_bounds__(1024, 4) void mlp_kernel(
        const float* __restrict__ X, int M,
        const float* __restrict__ W1, const float* __restrict__ b1,
        const float* __restrict__ W2, const float* __restrict__ b2,
        f16* __restrict__ Out) {
    __shared__ f16 W1T[128 * 136];
    __shared__ f16 W2T[(MODE == 0) ? 128 * 136 : 8];
    __shared__ f16 xBuf[256 * 136];
    __shared__ float bias1[128];
    __shared__ float bias2[128];
    int tid = threadIdx.x;

    stage_WT(W1, W1T, tid, 1024);
    if (MODE == 0) stage_WT(W2, W2T, tid, 1024);
    if (tid < 128) { bias1[tid] = b1[tid]; bias2[tid] = (MODE == 0) ? b2[tid] : 0.0f; }

    int r0 = blockIdx.x * 256;
    for (int it = 0; it < 8; ++it) {
        int row = it * 32 + (tid >> 5);
        int c4 = (tid & 31) * 4;
        int gr = r0 + row;
        floatx4 x = {0.0f, 0.0f, 0.0f, 0.0f};
        if (gr < M) x = *(const floatx4*)(X + (size_t)gr * 128 + c4);
        half4 xh;
        xh[0] = (f16)x[0]; xh[1] = (f16)x[1]; xh[2] = (f16)x[2]; xh[3] = (f16)x[3];
        *(half4*)(xBuf + row * 136 + c4) = xh;
    }
    __syncthreads();

    int lane = tid & 63, wv = tid >> 6;
    int R = wv * 16;
    int n16 = lane & 15, q = lane >> 4;
    int gr = r0 + R + n16;

    half8 a[4];
    #pragma unroll
    for (int kk = 0; kk < 4; ++kk)
        a[kk] = *(const half8*)(xBuf + (R + n16) * 136 + kk * 32 + q * 8);

    #pragma unroll
    for (int f = 0; f < 8; ++f) {
        floatx4 acc = *(const floatx4*)(bias1 + f * 16 + q * 4);
        #pragma unroll
        for (int kk = 0; kk < 4; ++kk) {
            half8 aw = *(const half8*)(W1T + (f * 16 + n16) * 136 + kk * 32 + q * 8);
            acc = __builtin_amdgcn_mfma_f32_16x16x32_f16(aw, a[kk], acc, 0, 0, 0);
        }
        if (MODE == 0) {
            half4 y;
            #pragma unroll
            for (int i = 0; i < 4; ++i) y[i] = (f16)fmaxf(acc[i], 0.0f);
            *(half4*)(xBuf + (R + n16) * 136 + f * 16 + q * 4) = y;
        } else {
            half4 o;
            #pragma unroll
            for (int i = 0; i < 4; ++i) o[i] = (f16)acc[i];
            if (gr < M) *(half4*)(Out + (size_t)gr * 128 + f * 16 + q * 4) = o;
        }
    }

    if (MODE == 0) {
        #pragma unroll
        for (int kk = 0; kk < 4; ++kk)
            a[kk] = *(const half8*)(xBuf + (R + n16) * 136 + kk * 32 + q * 8);
        #pragma unroll
        for (int f = 0; f < 8; ++f) {
            floatx4 acc = *(const floatx4*)(bias2 + f * 16 + q * 4);
            #pragma unroll
            for (int kk = 0; kk < 4; ++kk) {
                half8 aw = *(const half8*)(W2T + (f * 16 + n16) * 136 + kk * 32 + q * 8);
                acc = __builtin_amdgcn_mfma_f32_16x16x32_f16(aw, a[kk], acc, 0, 0, 0);
            }
            half4 o;
            #pragma unroll
            for (int i = 0; i < 4; ++i) o[i] = (f16)acc[i];
            if (gr < M) *(half4*)(Out + (size_t)gr * 128 + f * 16 + q * 4) = o;
        }
    }
}

// ---------------------------------------------------------------------------
// Barrier-free edge kernel, 32-edge chunks, weight-fragment sharing.
// 16 waves/block, 1 block/CU, wave-local. Per chunk (two 16-edge sub-tiles):
//   B0/B1: u = relu(T(global,C-layout) + rbf@W1r)  -> U region (time-shared)
//   C: ep = u@We2+be2, W2T frags shared (1 read -> 2 MFMAs); ep1 parked in regs
//   E: m = tanh((P⊙ep)@Wc+bc), WcT frags shared; mT = 32 rows x 64 cols,
//      two half-column passes (cols 0-63 then 64-127), F after each.
//   F: segment reduce; dst via v_readlane (scalar branch), no LDS dW.
// ---------------------------------------------------------------------------
__global__ __launch_bounds__(1024, 4) void edge_kernel(
        const uint4* __restrict__ packE,
        const f16* __restrict__ P, const f16* __restrict__ T,
        const float* __restrict__ We1,
        const float* __restrict__ We2, const float* __restrict__ be2,
        const float* __restrict__ Wc,  const float* __restrict__ bc,
        float* __restrict__ h) {
    __shared__ f16 W2T[128 * 136];       // 34816 B
    __shared__ f16 WcT[128 * 136];       // 34816 B
    __shared__ f16 W1rT[128 * 40];       // 10240 B
    __shared__ f16 Uall[16 * 2176];      // 69632 B : per-wave u/ep (16x136) then mT (64x32)
    __shared__ float sbe2[128], sbc[128];
    // total ~150.5 KB -> 1 block/CU, 16 waves

    int tid = threadIdx.x;
    stage_WT(We2, W2T, tid, 1024);
    stage_WT(Wc,  WcT, tid, 1024);
    for (int idx = tid; idx < 128 * 32; idx += 1024) {
        int n = idx >> 5, kr = idx & 31;
        W1rT[n * 40 + kr] = (kr < 30) ? (f16)We1[(128 + kr) * 128 + n] : (f16)0.0f;
    }
    if (tid < 128) { sbe2[tid] = be2[tid]; sbc[tid] = bc[tid]; }
    __syncthreads();    // weights ready; the ONLY block barrier

    int lane = tid & 63, wv = tid >> 6;
    f16* U = Uall + wv * 2176;
    int n16 = lane & 15, q = lane >> 4;
    const float invgap = 29.0f / 10.0f;

    float sbcv[8];
    #pragma unroll
    for (int f = 0; f < 8; ++f) sbcv[f] = sbc[f * 16 + n16];

    // balanced partition: 25000 chunks over 4096 waves (6 or 7 each)
    int wgid = blockIdx.x * 16 + wv;
    int extra = wgid < 424 ? wgid : 424;
    int c0 = wgid * 6 + extra;
    int c1 = c0 + 6 + (wgid < 424 ? 1 : 0);

    float carryA = 0.0f, carryB = 0.0f;
    int prev = -1;

    // prologue: pk for chunk c0 (32 records on lanes 0..31)
    uint4 pk = {0u, 0u, 0u, 0u};
    if (lane < 32) pk = packE[(size_t)c0 * 32 + lane];

    for (int ch = c0; ch < c1; ++ch) {
        // ---- prefetch next pk (sequential, cheap) -------------------------
        uint4 pkn = {0u, 0u, 0u, 0u};
        if (ch + 1 < c1 && lane < 32) pkn = packE[(size_t)(ch + 1) * 32 + lane];

        // ---- distribute (bpermute) ----------------------------------------
        int   ety0 = __shfl((int)pk.y, n16);
        int   ety1 = __shfl((int)pk.y, 16 + n16);
        int   src0 = __shfl((int)pk.x, n16);
        int   src1 = __shfl((int)pk.x, 16 + n16);
        float d0   = __shfl(__uint_as_float(pk.w), n16);
        float d1   = __shfl(__uint_as_float(pk.w), 16 + n16);

        // ---- T loads for both subs (C-layout direct; T is L2-hot) ---------
        half4 t0[8], t1[8];
        {
            const f16* Tp0 = T + (size_t)ety0 * 128 + q * 4;
            const f16* Tp1 = T + (size_t)ety1 * 128 + q * 4;
            #pragma unroll
            for (int f = 0; f < 8; ++f) {
                t0[f] = *(const half4*)(Tp0 + f * 16);
                t1[f] = *(const half4*)(Tp1 + f * 16);
            }
        }

        // ---- rbf fragments ------------------------------------------------
        half8 ar0, ar1;
        #pragma unroll
        for (int j = 0; j < 8; ++j) {
            int k = q * 8 + j;
            float c = (float)k * (10.0f / 29.0f);
            float df0 = d0 - c, df1 = d1 - c;
            ar0[j] = (f16)((k < 30) ? __expf(-df0 * df0 * invgap) : 0.0f);
            ar1[j] = (f16)((k < 30) ? __expf(-df1 * df1 * invgap) : 0.0f);
        }

        // ---- B0: u0 -> U; a2_0 -> regs ------------------------------------
        half8 a20[4], a21[4];
        #pragma unroll
        for (int f = 0; f < 8; ++f) {
            half4 tv = t0[f];
            floatx4 c4 = {(float)tv[0], (float)tv[1], (float)tv[2], (float)tv[3]};
            half8 aw = *(const half8*)(W1rT + (f * 16 + n16) * 40 + q * 8);
            c4 = __builtin_amdgcn_mfma_f32_16x16x32_f16(aw, ar0, c4, 0, 0, 0);
            half4 uv;
            #pragma unroll
            for (int i = 0; i < 4; ++i) uv[i] = (f16)fmaxf(c4[i], 0.0f);
            *(half4*)(U + n16 * 136 + f * 16 + q * 4) = uv;
        }
        #pragma unroll
        for (int kk = 0; kk < 4; ++kk)
            a20[kk] = *(const half8*)(U + n16 * 136 + kk * 32 + q * 8);

        // ---- B1: u1 -> U (overwrite); a2_1 -> regs ------------------------
        #pragma unroll
        for (int f = 0; f < 8; ++f) {
            half4 tv = t1[f];
            floatx4 c4 = {(float)tv[0], (float)tv[1], (float)tv[2], (float)tv[3]};
            half8 aw = *(const half8*)(W1rT + (f * 16 + n16) * 40 + q * 8);
            c4 = __builtin_amdgcn_mfma_f32_16x16x32_f16(aw, ar1, c4, 0, 0, 0);
            half4 uv;
            #pragma unroll
            for (int i = 0; i < 4; ++i) uv[i] = (f16)fmaxf(c4[i], 0.0f);
            *(half4*)(U + n16 * 136 + f * 16 + q * 4) = uv;
        }
        #pragma unroll
        for (int kk = 0; kk < 4; ++kk)
            a21[kk] = *(const half8*)(U + n16 * 136 + kk * 32 + q * 8);

        // ---- issue P loads (A-layout rows for both subs) ------------------
        half8 pA0[4], pA1[4];
        {
            const f16* Pr0 = P + (size_t)src0 * 128 + q * 8;
            const f16* Pr1 = P + (size_t)src1 * 128 + q * 8;
            #pragma unroll
            for (int kk = 0; kk < 4; ++kk) {
                pA0[kk] = *(const half8*)(Pr0 + kk * 32);
                pA1[kk] = *(const half8*)(Pr1 + kk * 32);
            }
        }

        // ---- C (shared W2T): ep0 -> U, ep1 -> regs ------------------------
        half4 ep1r[8];
        #pragma unroll
        for (int f = 0; f < 8; ++f) {
            floatx4 acc0 = *(const floatx4*)(sbe2 + f * 16 + q * 4);
            floatx4 acc1 = acc0;
            #pragma unroll
            for (int kk = 0; kk < 4; ++kk) {
                half8 aw = *(const half8*)(W2T + (f * 16 + n16) * 136 + kk * 32 + q * 8);
                acc0 = __builtin_amdgcn_mfma_f32_16x16x32_f16(aw, a20[kk], acc0, 0, 0, 0);
                acc1 = __builtin_amdgcn_mfma_f32_16x16x32_f16(aw, a21[kk], acc1, 0, 0, 0);
            }
            half4 e0;
            #pragma unroll
            for (int i = 0; i < 4; ++i) e0[i] = (f16)acc0[i];
            *(half4*)(U + n16 * 136 + f * 16 + q * 4) = e0;
            half4 e1;
            #pragma unroll
            for (int i = 0; i < 4; ++i) e1[i] = (f16)acc1[i];
            ep1r[f] = e1;
        }

        // ---- a2e_0 = ep0 ⊙ P0; park ep1; a2e_1 = ep1 ⊙ P1 -----------------
        half8 a2e0[4], a2e1[4];
        #pragma unroll
        for (int kk = 0; kk < 4; ++kk) {
            half8 e = *(const half8*)(U + n16 * 136 + kk * 32 + q * 8);
            a2e0[kk] = e * pA0[kk];
        }
        #pragma unroll
        for (int f = 0; f < 8; ++f)
            *(half4*)(U + n16 * 136 + f * 16 + q * 4) = ep1r[f];
        #pragma unroll
        for (int kk = 0; kk < 4; ++kk) {
            half8 e = *(const half8*)(U + n16 * 136 + kk * 32 + q * 8);
            a2e1[kk] = e * pA1[kk];
        }

        // ---- E + F in two half-column passes ------------------------------
        int prevIn = prev;
        int prevOut = prev;
        #pragma unroll
        for (int p = 0; p < 2; ++p) {
            // E: feats f = p*4 .. p*4+3, shared WcT frags, both subs
            #pragma unroll
            for (int fo = 0; fo < 4; ++fo) {
                int f = p * 4 + fo;
                float bb = sbcv[f];
                floatx4 acc0 = {bb, bb, bb, bb};
                floatx4 acc1 = {bb, bb, bb, bb};
                #pragma unroll
                for (int kk = 0; kk < 4; ++kk) {
                    half8 bw = *(const half8*)(WcT + (f * 16 + n16) * 136 + kk * 32 + q * 8);
                    acc0 = __builtin_amdgcn_mfma_f32_16x16x32_f16(a2e0[kk], bw, acc0, 0, 0, 0);
                    acc1 = __builtin_amdgcn_mfma_f32_16x16x32_f16(a2e1[kk], bw, acc1, 0, 0, 0);
                }
                int cs = fo * 16 + n16;                 // storage col 0..63
                half4 m0, m1;
                #pragma unroll
                for (int i = 0; i < 4; ++i) { m0[i] = (f16)fast_tanh(acc0[i]); m1[i] = (f16)fast_tanh(acc1[i]); }
                *(half4*)(U + cs * 32 + ((((cs >> 2) + q) & 7) << 2)) = m0;      // rows q*4..+3
                *(half4*)(U + cs * 32 + ((((cs >> 2) + 4 + q) & 7) << 2)) = m1;  // rows 16+q*4..+3
            }
            // F: segment reduce, cols p*64 + lane, rows 0..31
            {
                half4 v[8];
                #pragma unroll
                for (int rg = 0; rg < 8; ++rg)
                    v[rg] = *(const half4*)(U + lane * 32 + ((((lane >> 2) + rg) & 7) << 2));
                float cr = (p == 0) ? carryA : carryB;
                int pv = prevIn;
                float* hc = h + (size_t)p * 64 + lane;
                #pragma unroll
                for (int r = 0; r < 32; ++r) {
                    int dd = __shfl((int)pk.z, r);      // v_readlane -> scalar
                    float val = (float)v[r >> 2][r & 3];
                    if (dd != pv) {                      // wave-uniform branch
                        if (pv >= 0) unsafeAtomicAdd(hc + (size_t)pv * 128, cr);
                        pv = dd; cr = val;
                    } else cr += val;
                }
                if (p == 0) carryA = cr; else carryB = cr;
                prevOut = pv;
            }
        }
        prev = prevOut;
        pk = pkn;
    }
    if (prev >= 0) {
        unsafeAtomicAdd(&h[(size_t)prev * 128 + lane], carryA);
        unsafeAtomicAdd(&h[(size_t)prev * 128 + 64 + lane], carryB);
    }
}

// fused readout: hr = relu(h@Wr1+br1)·Wr2 + br2, out[gid] += hr  (per row)
__global__ __launch_bounds__(1024, 4) void readout_k(
        const float* __restrict__ X, int M,
        const float* __restrict__ W1, const float* __restrict__ b1,
        const float* __restrict__ Wr2, const float* __restrict__ br2,
        const int* __restrict__ gid, float* __restrict__ out) {
    __shared__ f16 W1T[128 * 136];
    __shared__ f16 xBuf[256 * 136];
    __shared__ float bias1[128];
    __shared__ float sWr2[128];
    int tid = threadIdx.x;

    stage_WT(W1, W1T, tid, 1024);
    if (tid < 128) { bias1[tid] = b1[tid]; sWr2[tid] = Wr2[tid]; }

    int r0 = blockIdx.x * 256;
    for (int it = 0; it < 8; ++it) {
        int row = it * 32 + (tid >> 5);
        int c4 = (tid & 31) * 4;
        int gr = r0 + row;
        floatx4 x = {0.0f, 0.0f, 0.0f, 0.0f};
        if (gr < M) x = *(const floatx4*)(X + (size_t)gr * 128 + c4);
        half4 xh;
        xh[0] = (f16)x[0]; xh[1] = (f16)x[1]; xh[2] = (f16)x[2]; xh[3] = (f16)x[3];
        *(half4*)(xBuf + row * 136 + c4) = xh;
    }
    __syncthreads();

    int lane = tid & 63, wv = tid >> 6;
    int R = wv * 16;
    int n16 = lane & 15, q = lane >> 4;

    half8 a[4];
    #pragma unroll
    for (int kk = 0; kk < 4; ++kk)
        a[kk] = *(const half8*)(xBuf + (R + n16) * 136 + kk * 32 + q * 8);

    floatx4 acc[8];
    #pragma unroll
    for (int f = 0; f < 8; ++f) {
        float bb = bias1[f * 16 + n16];
        acc[f] = (floatx4){bb, bb, bb, bb};
        #pragma unroll
        for (int kk = 0; kk < 4; ++kk) {
            half8 b = *(const half8*)(W1T + (f * 16 + n16) * 136 + kk * 32 + q * 8);
            acc[f] = __builtin_amdgcn_mfma_f32_16x16x32_f16(a[kk], b, acc[f], 0, 0, 0);
        }
    }

    float s[4];
    #pragma unroll
    for (int i = 0; i < 4; ++i) {
        float t = 0.0f;
        #pragma unroll
        for (int f = 0; f < 8; ++f)
            t += fmaxf(acc[f][i], 0.0f) * sWr2[f * 16 + n16];
        #pragma unroll
        for (int m = 1; m < 16; m <<= 1) t += __shfl_xor(t, m);
        s[i] = t;
    }

    if (n16 == 0) {
        float br2v = br2[0];
        float t = 0.0f; int g = -1;
        #pragma unroll
        for (int i = 0; i < 4; ++i) {
            int gr = r0 + R + q * 4 + i;
            if (gr < M) {
                int gi = gid[gr];
                float si = s[i] + br2v;
                if (gi == g) t += si;
                else { if (g >= 0) unsafeAtomicAdd(&out[g], t); g = gi; t = si; }
            }
        }
        if (g >= 0) unsafeAtomicAdd(&out[g], t);
    }
}

extern "C" void kernel_launch(void* const* d_in, const int* in_sizes, int n_in,
                              void* d_out, int out_size, void* d_ws, size_t ws_size,
                              hipStream_t stream) {
    (void)in_sizes; (void)n_in; (void)ws_size;
    const int*   node_types = (const int*)d_in[0];
    const int*   edge_types = (const int*)d_in[1];
    const int*   src        = (const int*)d_in[2];
    const int*   dst        = (const int*)d_in[3];
    const int*   graph_ids  = (const int*)d_in[4];
    const float* distances  = (const float*)d_in[5];
    const float* node_emb   = (const float*)d_in[7];
    const float* edge_emb   = (const float*)d_in[8];
    const float* Wn1 = (const float*)d_in[9];
    const float* bn1 = (const float*)d_in[10];
    const float* Wn2 = (const float*)d_in[11];
    const float* bn2 = (const float*)d_in[12];
    const float* We1 = (const float*)d_in[13];
    const float* be1 = (const float*)d_in[14];
    const float* We2 = (const float*)d_in[15];
    const float* be2 = (const float*)d_in[16];
    const float* Wc  = (const float*)d_in[17];
    const float* bc  = (const float*)d_in[18];
    const float* Wr1 = (const float*)d_in[19];
    const float* br1 = (const float*)d_in[20];
    const float* Wr2 = (const float*)d_in[21];
    const float* br2 = (const float*)d_in[22];

    char* w = (char*)d_ws;
    auto carve = [&](size_t bytes) { char* p = w; w += (bytes + 255) & ~(size_t)255; return p; };
    float* h        = (float*)carve((size_t)NNODES * 128 * 4);
    f16*   P        = (f16*)  carve((size_t)NNODES * 128 * 2);
    f16*   T        = (f16*)  carve((size_t)500 * 128 * 2);
    int*   rowStart = (int*)  carve((size_t)(NNODES + 1) * 4);
    int*   cnt      = (int*)  carve((size_t)NNODES * 4);
    int*   blockSum = (int*)  carve((size_t)64 * 4);
    uint4* packE    = (uint4*)carve((size_t)NEDGES * 16);

    float* out = (float*)d_out;
    const int NB1 = (NNODES + 1023) / 1024;   // 49

    init_k<<<(NNODES + 255) / 256, 256, 0, stream>>>(out, out_size, cnt);
    hist_k<<<NEDGES / 256, 256, 0, stream>>>(dst, cnt);
    scan1_k<<<NB1, 1024, 0, stream>>>(cnt, rowStart, blockSum);
    scan2_k<<<1, 64, 0, stream>>>(blockSum, NB1);
    scan3_k<<<NB1, 1024, 0, stream>>>(rowStart, blockSum, cnt);
    scatter_k<<<NEDGES / 256, 256, 0, stream>>>(src, edge_types, dst, distances,
                                                rowStart, cnt, packE);
    gather_h<<<(NNODES * 32 + 255) / 256, 256, 0, stream>>>(node_types, node_emb, h);

    for (int i = 0; i < 3; ++i) {
        mlp_kernel<2><<<(500 + 255) / 256, 1024, 0, stream>>>(
            edge_emb, 500, We1 + (size_t)i * 158 * 128, be1 + i * 128, nullptr, nullptr, T);
        mlp_kernel<0><<<(NNODES + 255) / 256, 1024, 0, stream>>>(
            h, NNODES, Wn1 + (size_t)i * 128 * 128, bn1 + i * 128,
            Wn2 + (size_t)i * 128 * 128, bn2 + i * 128, P);
        edge_kernel<<<256, 1024, 0, stream>>>(
            packE, P, T,
            We1 + (size_t)i * 158 * 128,
            We2 + (size_t)i * 128 * 128, be2 + i * 128,
            Wc + (size_t)i * 128 * 128, bc + i * 128, h);
    }

    readout_k<<<(NNODES + 255) / 256, 1024, 0, stream>>>(
        h, NNODES, Wr1, br1, Wr2, br2, graph_ids, out);
}

// Round 10
// 786.947 us; speedup vs baseline: 1.6151x; 1.6151x over previous
//
#include <hip/hip_runtime.h>
#include <stdint.h>

#define NNODES 50000
#define NEDGES 800000
#define NGRAPH 100
#define NCHUNK (NEDGES / 16)   // 50000 16-edge chunks
#define NWAVES 4096            // 256 blocks x 16 waves

typedef _Float16 f16;
typedef __attribute__((ext_vector_type(8))) _Float16 half8;
typedef __attribute__((ext_vector_type(4))) _Float16 half4;
typedef __attribute__((ext_vector_type(4))) float floatx4;

// stage 128x128 fp32 row-major W[k][n] -> LDS WT[n][136 pad] fp16, float4 loads
__device__ __forceinline__ void stage_WT(const float* __restrict__ W, f16* WT,
                                         int tid, int nthr) {
    for (int idx = tid; idx < 128 * 32; idx += nthr) {
        int k = idx >> 5, n4 = (idx & 31) * 4;
        floatx4 v = *(const floatx4*)(W + k * 128 + n4);
        WT[(n4 + 0) * 136 + k] = (f16)v[0];
        WT[(n4 + 1) * 136 + k] = (f16)v[1];
        WT[(n4 + 2) * 136 + k] = (f16)v[2];
        WT[(n4 + 3) * 136 + k] = (f16)v[3];
    }
}

__device__ __forceinline__ float fast_tanh(float x) {
    x = fminf(fmaxf(x, -15.0f), 15.0f);
    float e2 = __expf(2.0f * x);
    return (e2 - 1.0f) * __builtin_amdgcn_rcpf(e2 + 1.0f);
}

// transposed-m: column c owns f16 elements [c*16, c*16+16); row groups of 4
// rotated by (c>>2) to spread banks. Bijective per column -> collision-free.
__device__ __forceinline__ int mtAddr(int c, int rgroup) {
    return c * 16 + ((((c >> 2) + rgroup) & 3) << 2);
}

__global__ void init_k(float* out, int osz, int* cnt) {
    int i = blockIdx.x * 256 + threadIdx.x;
    if (i < osz) out[i] = 0.0f;
    if (i < NNODES) cnt[i] = 0;
}

__global__ void hist_k(const int* __restrict__ dst, int* __restrict__ cnt) {
    int e = blockIdx.x * 256 + threadIdx.x;
    if (e < NEDGES) atomicAdd(&cnt[dst[e]], 1);
}

__global__ __launch_bounds__(1024) void scan1_k(const int* __restrict__ cnt,
                                                int* __restrict__ rowStart,
                                                int* __restrict__ blockSum) {
    __shared__ int buf[1024];
    int tid = threadIdx.x;
    int i = blockIdx.x * 1024 + tid;
    int v = (i < NNODES) ? cnt[i] : 0;
    buf[tid] = v;
    __syncthreads();
    for (int off = 1; off < 1024; off <<= 1) {
        int t = (tid >= off) ? buf[tid - off] : 0;
        __syncthreads();
        buf[tid] += t;
        __syncthreads();
    }
    if (i < NNODES) rowStart[i] = buf[tid] - v;
    if (tid == 1023) blockSum[blockIdx.x] = buf[1023];
}

__global__ void scan2_k(int* __restrict__ blockSum, int nb) {
    if (threadIdx.x == 0) {
        int run = 0;
        for (int b = 0; b < nb; ++b) { int s = blockSum[b]; blockSum[b] = run; run += s; }
    }
}

__global__ __launch_bounds__(1024) void scan3_k(int* __restrict__ rowStart,
                                                const int* __restrict__ blockSum,
                                                int* __restrict__ cnt) {
    int i = blockIdx.x * 1024 + threadIdx.x;
    if (i < NNODES) { rowStart[i] += blockSum[blockIdx.x]; cnt[i] = 0; }
    if (i == 0) rowStart[NNODES] = NEDGES;
}

__global__ void scatter_k(const int* __restrict__ src, const int* __restrict__ et,
                          const int* __restrict__ dst, const float* __restrict__ dist,
                          const int* __restrict__ rowStart, int* __restrict__ cnt,
                          uint4* __restrict__ packE) {
    int e = blockIdx.x * 256 + threadIdx.x;
    if (e >= NEDGES) return;
    int d = dst[e];
    int pos = rowStart[d] + atomicAdd(&cnt[d], 1);
    uint4 pk;
    pk.x = (unsigned)src[e];
    pk.y = (unsigned)et[e];
    pk.z = (unsigned)d;
    pk.w = __float_as_uint(dist[e]);
    packE[pos] = pk;
}

__global__ void gather_h(const int* __restrict__ nt, const float* __restrict__ emb,
                         float* __restrict__ h) {
    int i = blockIdx.x * 256 + threadIdx.x;
    int row = i >> 5, c4 = (i & 31) * 4;
    if (row < NNODES)
        *(floatx4*)(h + row * 128 + c4) = *(const floatx4*)(emb + nt[row] * 128 + c4);
}

// MODE 0: relu(X@W1+b1)@W2+b2 -> Out f16   MODE 2: X@W1+b1 -> Out f16
// Operand-swapped MFMAs -> feature-contiguous C-layout, all LDS b64/b128.
template <int MODE>
__global__ __launch_bounds__(1024, 4) void mlp_kernel(
        const float* __restrict__ X, int M,
        const float* __restrict__ W1, const float* __restrict__ b1,
        const float* __restrict__ W2, const float* __restrict__ b2,
        f16* __restrict__ Out) {
    __shared__ f16 W1T[128 * 136];
    __shared__ f16 W2T[(MODE == 0) ? 128 * 136 : 8];
    __shared__ f16 xBuf[256 * 136];
    __shared__ float bias1[128];
    __shared__ float bias2[128];
    int tid = threadIdx.x;

    stage_WT(W1, W1T, tid, 1024);
    if (MODE == 0) stage_WT(W2, W2T, tid, 1024);
    if (tid < 128) { bias1[tid] = b1[tid]; bias2[tid] = (MODE == 0) ? b2[tid] : 0.0f; }

    int r0 = blockIdx.x * 256;
    for (int it = 0; it < 8; ++it) {
        int row = it * 32 + (tid >> 5);
        int c4 = (tid & 31) * 4;
        int gr = r0 + row;
        floatx4 x = {0.0f, 0.0f, 0.0f, 0.0f};
        if (gr < M) x = *(const floatx4*)(X + (size_t)gr * 128 + c4);
        half4 xh;
        xh[0] = (f16)x[0]; xh[1] = (f16)x[1]; xh[2] = (f16)x[2]; xh[3] = (f16)x[3];
        *(half4*)(xBuf + row * 136 + c4) = xh;
    }
    __syncthreads();

    int lane = tid & 63, wv = tid >> 6;
    int R = wv * 16;
    int n16 = lane & 15, q = lane >> 4;
    int gr = r0 + R + n16;

    half8 a[4];
    #pragma unroll
    for (int kk = 0; kk < 4; ++kk)
        a[kk] = *(const half8*)(xBuf + (R + n16) * 136 + kk * 32 + q * 8);

    #pragma unroll
    for (int f = 0; f < 8; ++f) {
        floatx4 acc = *(const floatx4*)(bias1 + f * 16 + q * 4);
        #pragma unroll
        for (int kk = 0; kk < 4; ++kk) {
            half8 aw = *(const half8*)(W1T + (f * 16 + n16) * 136 + kk * 32 + q * 8);
            acc = __builtin_amdgcn_mfma_f32_16x16x32_f16(aw, a[kk], acc, 0, 0, 0);
        }
        if (MODE == 0) {
            half4 y;
            #pragma unroll
            for (int i = 0; i < 4; ++i) y[i] = (f16)fmaxf(acc[i], 0.0f);
            *(half4*)(xBuf + (R + n16) * 136 + f * 16 + q * 4) = y;
        } else {
            half4 o;
            #pragma unroll
            for (int i = 0; i < 4; ++i) o[i] = (f16)acc[i];
            if (gr < M) *(half4*)(Out + (size_t)gr * 128 + f * 16 + q * 4) = o;
        }
    }

    if (MODE == 0) {
        #pragma unroll
        for (int kk = 0; kk < 4; ++kk)
            a[kk] = *(const half8*)(xBuf + (R + n16) * 136 + kk * 32 + q * 8);
        #pragma unroll
        for (int f = 0; f < 8; ++f) {
            floatx4 acc = *(const floatx4*)(bias2 + f * 16 + q * 4);
            #pragma unroll
            for (int kk = 0; kk < 4; ++kk) {
                half8 aw = *(const half8*)(W2T + (f * 16 + n16) * 136 + kk * 32 + q * 8);
                acc = __builtin_amdgcn_mfma_f32_16x16x32_f16(aw, a[kk], acc, 0, 0, 0);
            }
            half4 o;
            #pragma unroll
            for (int i = 0; i < 4; ++i) o[i] = (f16)acc[i];
            if (gr < M) *(half4*)(Out + (size_t)gr * 128 + f * 16 + q * 4) = o;
        }
    }
}

// ---------------------------------------------------------------------------
// Barrier-free edge kernel. 16 waves/block, 1 block/CU, wave-local 16-edge
// chunks. All LDS ops b64/b128 (operand-swapped MFMAs). SEQUENTIAL memory
// schedule (the R6 schedule, counter-proven FETCH=80 MB): T loads drain into
// the LDS store BEFORE P loads issue -> in-flight row set per wave is 16, not
// 32, so the per-XCD L2 (4 MB) holds the working set. R7/R9's concurrent T+P
// schedules thrashed L2 (FETCH 393/514 MB). pk for the next chunk is
// prefetched (16 B x 16 lanes, negligible).
// ---------------------------------------------------------------------------
__global__ __launch_bounds__(1024, 4) void edge_kernel(
        const uint4* __restrict__ packE,
        const f16* __restrict__ P, const f16* __restrict__ T,
        const float* __restrict__ We1,
        const float* __restrict__ We2, const float* __restrict__ be2,
        const float* __restrict__ Wc,  const float* __restrict__ bc,
        float* __restrict__ h) {
    __shared__ f16 W2T[128 * 136];       // 34816 B
    __shared__ f16 WcT[128 * 136];       // 34816 B
    __shared__ f16 W1rT[128 * 40];       // 10240 B
    __shared__ f16 Uall[16 * 2176];      // 69632 B : per-wave 16x136 (T/u/ep) then mT
    __shared__ float sbe2[128], sbc[128];
    __shared__ int dstW[16][16];
    // total ~151.5 KB -> 1 block/CU, 16 waves

    int tid = threadIdx.x;
    stage_WT(We2, W2T, tid, 1024);
    stage_WT(Wc,  WcT, tid, 1024);
    for (int idx = tid; idx < 128 * 32; idx += 1024) {
        int n = idx >> 5, kr = idx & 31;
        W1rT[n * 40 + kr] = (kr < 30) ? (f16)We1[(128 + kr) * 128 + n] : (f16)0.0f;
    }
    if (tid < 128) { sbe2[tid] = be2[tid]; sbc[tid] = bc[tid]; }
    __syncthreads();    // weights ready; the ONLY block barrier

    int lane = tid & 63, wv = tid >> 6;
    f16* U = Uall + wv * 2176;
    int* dW = dstW[wv];
    int n16 = lane & 15, q = lane >> 4;
    const float invgap = 29.0f / 10.0f;
    int colA = lane, colB = lane + 64;
    int tsub = lane & 3, trow = lane >> 2;

    float sbcv[8];
    #pragma unroll
    for (int f = 0; f < 8; ++f) sbcv[f] = sbc[f * 16 + n16];

    // balanced stripe partition: 50000 chunks over 4096 waves (12 or 13 each)
    int wgid = blockIdx.x * 16 + wv;
    int extra = wgid < 848 ? wgid : 848;
    int c0 = wgid * 12 + extra;
    int c1 = c0 + 12 + (wgid < 848 ? 1 : 0);

    float carry0 = 0.0f, carry1 = 0.0f;
    int prev = -1;

    // prologue: pk for chunk c0
    uint4 pk = {0u, 0u, 0u, 0u};
    if (lane < 16) pk = packE[(size_t)c0 * 16 + lane];

    for (int ch = c0; ch < c1; ++ch) {
        bool hasNext = (ch + 1 < c1);
        // ---- distribute current records -----------------------------------
        int   ety  = __shfl((int)pk.y, trow);
        int   srcv = __shfl((int)pk.x, n16);
        float dcur = __shfl(__uint_as_float(pk.w), n16);
        if (lane < 16) dW[lane] = (int)pk.z;

        // ---- T loads, drained immediately into LDS (phase A) --------------
        {
            const uint4* Tp = (const uint4*)(T + (size_t)ety * 128 + tsub * 32);
            uint4 tr0 = Tp[0], tr1 = Tp[1], tr2 = Tp[2], tr3 = Tp[3];
            uint4* ub = (uint4*)(U + trow * 136 + tsub * 32);
            ub[0] = tr0; ub[1] = tr1; ub[2] = tr2; ub[3] = tr3;   // waits vmcnt(0)
        }

        // ---- NOW issue P loads (T no longer in flight) --------------------
        half8 pA0, pA1, pA2, pA3;
        {
            const f16* Pr = P + (size_t)srcv * 128 + q * 8;
            pA0 = *(const half8*)(Pr);
            pA1 = *(const half8*)(Pr + 32);
            pA2 = *(const half8*)(Pr + 64);
            pA3 = *(const half8*)(Pr + 96);
        }
        uint4 pkn = {0u, 0u, 0u, 0u};
        if (hasNext && lane < 16) pkn = packE[(size_t)(ch + 1) * 16 + lane];

        // ---- rbf in regs (VALU overlaps P latency) ------------------------
        half8 ar;
        #pragma unroll
        for (int j = 0; j < 8; ++j) {
            int k = q * 8 + j;
            float c = (float)k * (10.0f / 29.0f);
            float df = dcur - c;
            ar[j] = (f16)((k < 30) ? __expf(-df * df * invgap) : 0.0f);
        }

        // ---- B: u^T = relu(W1r^T @ rbf^T + T^T)  (all b64/b128) -----------
        #pragma unroll
        for (int f = 0; f < 8; ++f) {
            f16* up = U + n16 * 136 + f * 16 + q * 4;
            half4 tv = *(const half4*)up;
            floatx4 c4 = {(float)tv[0], (float)tv[1], (float)tv[2], (float)tv[3]};
            half8 aw = *(const half8*)(W1rT + (f * 16 + n16) * 40 + q * 8);
            c4 = __builtin_amdgcn_mfma_f32_16x16x32_f16(aw, ar, c4, 0, 0, 0);
            half4 uv;
            #pragma unroll
            for (int i = 0; i < 4; ++i) uv[i] = (f16)fmaxf(c4[i], 0.0f);
            *(half4*)up = uv;
        }

        // ---- C: ep^T = W2^T @ u^T + be2 -----------------------------------
        half8 a2[4];
        #pragma unroll
        for (int kk = 0; kk < 4; ++kk)
            a2[kk] = *(const half8*)(U + n16 * 136 + kk * 32 + q * 8);
        #pragma unroll
        for (int f = 0; f < 8; ++f) {
            floatx4 acc = *(const floatx4*)(sbe2 + f * 16 + q * 4);
            #pragma unroll
            for (int kk = 0; kk < 4; ++kk) {
                half8 aw = *(const half8*)(W2T + (f * 16 + n16) * 136 + kk * 32 + q * 8);
                acc = __builtin_amdgcn_mfma_f32_16x16x32_f16(aw, a2[kk], acc, 0, 0, 0);
            }
            half4 ev;
            #pragma unroll
            for (int i = 0; i < 4; ++i) ev[i] = (f16)acc[i];
            *(half4*)(U + n16 * 136 + f * 16 + q * 4) = ev;
        }

        // ---- E: m = tanh((P ⊙ ep) @ Wc + bc); write mT (b64, swizzled) ----
        {
            half8 e0 = *(const half8*)(U + n16 * 136 + 0 * 32 + q * 8);
            half8 e1 = *(const half8*)(U + n16 * 136 + 1 * 32 + q * 8);
            half8 e2 = *(const half8*)(U + n16 * 136 + 2 * 32 + q * 8);
            half8 e3 = *(const half8*)(U + n16 * 136 + 3 * 32 + q * 8);
            a2[0] = e0 * pA0; a2[1] = e1 * pA1; a2[2] = e2 * pA2; a2[3] = e3 * pA3;
        }
        #pragma unroll
        for (int f = 0; f < 8; ++f) {
            float bb = sbcv[f];
            floatx4 acc = {bb, bb, bb, bb};
            #pragma unroll
            for (int kk = 0; kk < 4; ++kk) {
                half8 b = *(const half8*)(WcT + (f * 16 + n16) * 136 + kk * 32 + q * 8);
                acc = __builtin_amdgcn_mfma_f32_16x16x32_f16(a2[kk], b, acc, 0, 0, 0);
            }
            int c = f * 16 + n16;
            half4 mv;
            #pragma unroll
            for (int i = 0; i < 4; ++i) mv[i] = (f16)fast_tanh(acc[i]);
            *(half4*)(U + mtAddr(c, q)) = mv;
        }

        // ---- F: per-col segment reduce with cross-chunk carry -------------
        {
            half4 va[4], vb[4];
            #pragma unroll
            for (int g2 = 0; g2 < 4; ++g2) {
                va[g2] = *(const half4*)(U + mtAddr(colA, g2));
                vb[g2] = *(const half4*)(U + mtAddr(colB, g2));
            }
            int dArr[16];
            *(int4*)(dArr)      = *(const int4*)(dW);
            *(int4*)(dArr + 4)  = *(const int4*)(dW + 4);
            *(int4*)(dArr + 8)  = *(const int4*)(dW + 8);
            *(int4*)(dArr + 12) = *(const int4*)(dW + 12);
            #pragma unroll
            for (int r = 0; r < 16; ++r) {
                int dd = dArr[r];
                float v0 = (float)va[r >> 2][r & 3];
                float v1 = (float)vb[r >> 2][r & 3];
                if (dd != prev) {   // wave-uniform branch
                    if (prev >= 0) {
                        unsafeAtomicAdd(&h[(size_t)prev * 128 + colA], carry0);
                        unsafeAtomicAdd(&h[(size_t)prev * 128 + colB], carry1);
                    }
                    prev = dd; carry0 = v0; carry1 = v1;
                } else { carry0 += v0; carry1 += v1; }
            }
        }
        pk = pkn;
    }
    if (prev >= 0) {
        unsafeAtomicAdd(&h[(size_t)prev * 128 + colA], carry0);
        unsafeAtomicAdd(&h[(size_t)prev * 128 + colB], carry1);
    }
}

// fused readout: hr = relu(h@Wr1+br1)·Wr2 + br2, out[gid] += hr  (per row)
__global__ __launch_bounds__(1024, 4) void readout_k(
        const float* __restrict__ X, int M,
        const float* __restrict__ W1, const float* __restrict__ b1,
        const float* __restrict__ Wr2, const float* __restrict__ br2,
        const int* __restrict__ gid, float* __restrict__ out) {
    __shared__ f16 W1T[128 * 136];
    __shared__ f16 xBuf[256 * 136];
    __shared__ float bias1[128];
    __shared__ float sWr2[128];
    int tid = threadIdx.x;

    stage_WT(W1, W1T, tid, 1024);
    if (tid < 128) { bias1[tid] = b1[tid]; sWr2[tid] = Wr2[tid]; }

    int r0 = blockIdx.x * 256;
    for (int it = 0; it < 8; ++it) {
        int row = it * 32 + (tid >> 5);
        int c4 = (tid & 31) * 4;
        int gr = r0 + row;
        floatx4 x = {0.0f, 0.0f, 0.0f, 0.0f};
        if (gr < M) x = *(const floatx4*)(X + (size_t)gr * 128 + c4);
        half4 xh;
        xh[0] = (f16)x[0]; xh[1] = (f16)x[1]; xh[2] = (f16)x[2]; xh[3] = (f16)x[3];
        *(half4*)(xBuf + row * 136 + c4) = xh;
    }
    __syncthreads();

    int lane = tid & 63, wv = tid >> 6;
    int R = wv * 16;
    int n16 = lane & 15, q = lane >> 4;

    half8 a[4];
    #pragma unroll
    for (int kk = 0; kk < 4; ++kk)
        a[kk] = *(const half8*)(xBuf + (R + n16) * 136 + kk * 32 + q * 8);

    floatx4 acc[8];
    #pragma unroll
    for (int f = 0; f < 8; ++f) {
        float bb = bias1[f * 16 + n16];
        acc[f] = (floatx4){bb, bb, bb, bb};
        #pragma unroll
        for (int kk = 0; kk < 4; ++kk) {
            half8 b = *(const half8*)(W1T + (f * 16 + n16) * 136 + kk * 32 + q * 8);
            acc[f] = __builtin_amdgcn_mfma_f32_16x16x32_f16(a[kk], b, acc[f], 0, 0, 0);
        }
    }

    float s[4];
    #pragma unroll
    for (int i = 0; i < 4; ++i) {
        float t = 0.0f;
        #pragma unroll
        for (int f = 0; f < 8; ++f)
            t += fmaxf(acc[f][i], 0.0f) * sWr2[f * 16 + n16];
        #pragma unroll
        for (int m = 1; m < 16; m <<= 1) t += __shfl_xor(t, m);
        s[i] = t;
    }

    if (n16 == 0) {
        float br2v = br2[0];
        float t = 0.0f; int g = -1;
        #pragma unroll
        for (int i = 0; i < 4; ++i) {
            int gr = r0 + R + q * 4 + i;
            if (gr < M) {
                int gi = gid[gr];
                float si = s[i] + br2v;
                if (gi == g) t += si;
                else { if (g >= 0) unsafeAtomicAdd(&out[g], t); g = gi; t = si; }
            }
        }
        if (g >= 0) unsafeAtomicAdd(&out[g], t);
    }
}

extern "C" void kernel_launch(void* const* d_in, const int* in_sizes, int n_in,
                              void* d_out, int out_size, void* d_ws, size_t ws_size,
                              hipStream_t stream) {
    (void)in_sizes; (void)n_in; (void)ws_size;
    const int*   node_types = (const int*)d_in[0];
    const int*   edge_types = (const int*)d_in[1];
    const int*   src        = (const int*)d_in[2];
    const int*   dst        = (const int*)d_in[3];
    const int*   graph_ids  = (const int*)d_in[4];
    const float* distances  = (const float*)d_in[5];
    const float* node_emb   = (const float*)d_in[7];
    const float* edge_emb   = (const float*)d_in[8];
    const float* Wn1 = (const float*)d_in[9];
    const float* bn1 = (const float*)d_in[10];
    const float* Wn2 = (const float*)d_in[11];
    const float* bn2 = (const float*)d_in[12];
    const float* We1 = (const float*)d_in[13];
    const float* be1 = (const float*)d_in[14];
    const float* We2 = (const float*)d_in[15];
    const float* be2 = (const float*)d_in[16];
    const float* Wc  = (const float*)d_in[17];
    const float* bc  = (const float*)d_in[18];
    const float* Wr1 = (const float*)d_in[19];
    const float* br1 = (const float*)d_in[20];
    const float* Wr2 = (const float*)d_in[21];
    const float* br2 = (const float*)d_in[22];

    char* w = (char*)d_ws;
    auto carve = [&](size_t bytes) { char* p = w; w += (bytes + 255) & ~(size_t)255; return p; };
    float* h        = (float*)carve((size_t)NNODES * 128 * 4);
    f16*   P        = (f16*)  carve((size_t)NNODES * 128 * 2);
    f16*   T        = (f16*)  carve((size_t)500 * 128 * 2);
    int*   rowStart = (int*)  carve((size_t)(NNODES + 1) * 4);
    int*   cnt      = (int*)  carve((size_t)NNODES * 4);
    int*   blockSum = (int*)  carve((size_t)64 * 4);
    uint4* packE    = (uint4*)carve((size_t)NEDGES * 16);

    float* out = (float*)d_out;
    const int NB1 = (NNODES + 1023) / 1024;   // 49

    init_k<<<(NNODES + 255) / 256, 256, 0, stream>>>(out, out_size, cnt);
    hist_k<<<NEDGES / 256, 256, 0, stream>>>(dst, cnt);
    scan1_k<<<NB1, 1024, 0, stream>>>(cnt, rowStart, blockSum);
    scan2_k<<<1, 64, 0, stream>>>(blockSum, NB1);
    scan3_k<<<NB1, 1024, 0, stream>>>(rowStart, blockSum, cnt);
    scatter_k<<<NEDGES / 256, 256, 0, stream>>>(src, edge_types, dst, distances,
                                                rowStart, cnt, packE);
    gather_h<<<(NNODES * 32 + 255) / 256, 256, 0, stream>>>(node_types, node_emb, h);

    for (int i = 0; i < 3; ++i) {
        mlp_kernel<2><<<(500 + 255) / 256, 1024, 0, stream>>>(
            edge_emb, 500, We1 + (size_t)i * 158 * 128, be1 + i * 128, nullptr, nullptr, T);
        mlp_kernel<0><<<(NNODES + 255) / 256, 1024, 0, stream>>>(
            h, NNODES, Wn1 + (size_t)i * 128 * 128, bn1 + i * 128,
            Wn2 + (size_t)i * 128 * 128, bn2 + i * 128, P);
        edge_kernel<<<256, 1024, 0, stream>>>(
            packE, P, T,
            We1 + (size_t)i * 158 * 128,
            We2 + (size_t)i * 128 * 128, be2 + i * 128,
            Wc + (size_t)i * 128 * 128, bc + i * 128, h);
    }

    readout_k<<<(NNODES + 255) / 256, 1024, 0, stream>>>(
        h, NNODES, Wr1, br1, Wr2, br2, graph_ids, out);
}

// Round 11
// 715.337 us; speedup vs baseline: 1.7767x; 1.1001x over previous
//
#include <hip/hip_runtime.h>
#include <stdint.h>

#define NNODES 50000
#define NEDGES 800000
#define NGRAPH 100
#define NCHUNK (NEDGES / 16)   // 50000 16-edge chunks
#define NWAVES 4096            // 256 blocks x 16 waves

typedef _Float16 f16;
typedef __attribute__((ext_vector_type(8))) _Float16 half8;
typedef __attribute__((ext_vector_type(4))) _Float16 half4;
typedef __attribute__((ext_vector_type(4))) float floatx4;

// stage 128x128 fp32 row-major W[k][n] -> LDS WT[n][136 pad] fp16, float4 loads
__device__ __forceinline__ void stage_WT(const float* __restrict__ W, f16* WT,
                                         int tid, int nthr) {
    for (int idx = tid; idx < 128 * 32; idx += nthr) {
        int k = idx >> 5, n4 = (idx & 31) * 4;
        floatx4 v = *(const floatx4*)(W + k * 128 + n4);
        WT[(n4 + 0) * 136 + k] = (f16)v[0];
        WT[(n4 + 1) * 136 + k] = (f16)v[1];
        WT[(n4 + 2) * 136 + k] = (f16)v[2];
        WT[(n4 + 3) * 136 + k] = (f16)v[3];
    }
}

__device__ __forceinline__ float fast_tanh(float x) {
    x = fminf(fmaxf(x, -15.0f), 15.0f);
    float e2 = __expf(2.0f * x);
    return (e2 - 1.0f) * __builtin_amdgcn_rcpf(e2 + 1.0f);
}

// transposed-m: column c owns f16 elements [c*16, c*16+16); row groups of 4
// rotated by (c>>2) to spread banks. Bijective per column -> collision-free.
__device__ __forceinline__ int mtAddr(int c, int rgroup) {
    return c * 16 + ((((c >> 2) + rgroup) & 3) << 2);
}

__global__ void init_k(float* out, int osz, int* cnt) {
    int i = blockIdx.x * 256 + threadIdx.x;
    if (i < osz) out[i] = 0.0f;
    if (i < NNODES) cnt[i] = 0;
}

__global__ void hist_k(const int* __restrict__ dst, int* __restrict__ cnt) {
    int e = blockIdx.x * 256 + threadIdx.x;
    if (e < NEDGES) atomicAdd(&cnt[dst[e]], 1);
}

__global__ __launch_bounds__(1024) void scan1_k(const int* __restrict__ cnt,
                                                int* __restrict__ rowStart,
                                                int* __restrict__ blockSum) {
    __shared__ int buf[1024];
    int tid = threadIdx.x;
    int i = blockIdx.x * 1024 + tid;
    int v = (i < NNODES) ? cnt[i] : 0;
    buf[tid] = v;
    __syncthreads();
    for (int off = 1; off < 1024; off <<= 1) {
        int t = (tid >= off) ? buf[tid - off] : 0;
        __syncthreads();
        buf[tid] += t;
        __syncthreads();
    }
    if (i < NNODES) rowStart[i] = buf[tid] - v;
    if (tid == 1023) blockSum[blockIdx.x] = buf[1023];
}

__global__ void scan2_k(int* __restrict__ blockSum, int nb) {
    if (threadIdx.x == 0) {
        int run = 0;
        for (int b = 0; b < nb; ++b) { int s = blockSum[b]; blockSum[b] = run; run += s; }
    }
}

__global__ __launch_bounds__(1024) void scan3_k(int* __restrict__ rowStart,
                                                const int* __restrict__ blockSum,
                                                int* __restrict__ cnt) {
    int i = blockIdx.x * 1024 + threadIdx.x;
    if (i < NNODES) { rowStart[i] += blockSum[blockIdx.x]; cnt[i] = 0; }
    if (i == 0) rowStart[NNODES] = NEDGES;
}

__global__ void scatter_k(const int* __restrict__ src, const int* __restrict__ et,
                          const int* __restrict__ dst, const float* __restrict__ dist,
                          const int* __restrict__ rowStart, int* __restrict__ cnt,
                          uint4* __restrict__ packE) {
    int e = blockIdx.x * 256 + threadIdx.x;
    if (e >= NEDGES) return;
    int d = dst[e];
    int pos = rowStart[d] + atomicAdd(&cnt[d], 1);
    uint4 pk;
    pk.x = (unsigned)src[e];
    pk.y = (unsigned)et[e];
    pk.z = (unsigned)d;
    pk.w = __float_as_uint(dist[e]);
    packE[pos] = pk;
}

__global__ void gather_h(const int* __restrict__ nt, const float* __restrict__ emb,
                         float* __restrict__ h) {
    int i = blockIdx.x * 256 + threadIdx.x;
    int row = i >> 5, c4 = (i & 31) * 4;
    if (row < NNODES)
        *(floatx4*)(h + row * 128 + c4) = *(const floatx4*)(emb + nt[row] * 128 + c4);
}

// MODE 0: relu(X@W1+b1)@W2+b2 -> Out f16   MODE 2: X@W1+b1 -> Out f16
// Operand-swapped MFMAs -> feature-contiguous C-layout, all LDS b64/b128.
template <int MODE>
__global__ __launch_bounds__(1024, 4) void mlp_kernel(
        const float* __restrict__ X, int M,
        const float* __restrict__ W1, const float* __restrict__ b1,
        const float* __restrict__ W2, const float* __restrict__ b2,
        f16* __restrict__ Out) {
    __shared__ f16 W1T[128 * 136];
    __shared__ f16 W2T[(MODE == 0) ? 128 * 136 : 8];
    __shared__ f16 xBuf[256 * 136];
    __shared__ float bias1[128];
    __shared__ float bias2[128];
    int tid = threadIdx.x;

    stage_WT(W1, W1T, tid, 1024);
    if (MODE == 0) stage_WT(W2, W2T, tid, 1024);
    if (tid < 128) { bias1[tid] = b1[tid]; bias2[tid] = (MODE == 0) ? b2[tid] : 0.0f; }

    int r0 = blockIdx.x * 256;
    for (int it = 0; it < 8; ++it) {
        int row = it * 32 + (tid >> 5);
        int c4 = (tid & 31) * 4;
        int gr = r0 + row;
        floatx4 x = {0.0f, 0.0f, 0.0f, 0.0f};
        if (gr < M) x = *(const floatx4*)(X + (size_t)gr * 128 + c4);
        half4 xh;
        xh[0] = (f16)x[0]; xh[1] = (f16)x[1]; xh[2] = (f16)x[2]; xh[3] = (f16)x[3];
        *(half4*)(xBuf + row * 136 + c4) = xh;
    }
    __syncthreads();

    int lane = tid & 63, wv = tid >> 6;
    int R = wv * 16;
    int n16 = lane & 15, q = lane >> 4;
    int gr = r0 + R + n16;

    half8 a[4];
    #pragma unroll
    for (int kk = 0; kk < 4; ++kk)
        a[kk] = *(const half8*)(xBuf + (R + n16) * 136 + kk * 32 + q * 8);

    #pragma unroll
    for (int f = 0; f < 8; ++f) {
        floatx4 acc = *(const floatx4*)(bias1 + f * 16 + q * 4);
        #pragma unroll
        for (int kk = 0; kk < 4; ++kk) {
            half8 aw = *(const half8*)(W1T + (f * 16 + n16) * 136 + kk * 32 + q * 8);
            acc = __builtin_amdgcn_mfma_f32_16x16x32_f16(aw, a[kk], acc, 0, 0, 0);
        }
        if (MODE == 0) {
            half4 y;
            #pragma unroll
            for (int i = 0; i < 4; ++i) y[i] = (f16)fmaxf(acc[i], 0.0f);
            *(half4*)(xBuf + (R + n16) * 136 + f * 16 + q * 4) = y;
        } else {
            half4 o;
            #pragma unroll
            for (int i = 0; i < 4; ++i) o[i] = (f16)acc[i];
            if (gr < M) *(half4*)(Out + (size_t)gr * 128 + f * 16 + q * 4) = o;
        }
    }

    if (MODE == 0) {
        #pragma unroll
        for (int kk = 0; kk < 4; ++kk)
            a[kk] = *(const half8*)(xBuf + (R + n16) * 136 + kk * 32 + q * 8);
        #pragma unroll
        for (int f = 0; f < 8; ++f) {
            floatx4 acc = *(const floatx4*)(bias2 + f * 16 + q * 4);
            #pragma unroll
            for (int kk = 0; kk < 4; ++kk) {
                half8 aw = *(const half8*)(W2T + (f * 16 + n16) * 136 + kk * 32 + q * 8);
                acc = __builtin_amdgcn_mfma_f32_16x16x32_f16(aw, a[kk], acc, 0, 0, 0);
            }
            half4 o;
            #pragma unroll
            for (int i = 0; i < 4; ++i) o[i] = (f16)acc[i];
            if (gr < M) *(half4*)(Out + (size_t)gr * 128 + f * 16 + q * 4) = o;
        }
    }
}

// ---------------------------------------------------------------------------
// Barrier-free edge kernel. 16 waves/block, 1 block/CU, wave-local 16-edge
// chunks, all LDS ops b64/b128 (operand-swapped MFMAs).
// MEMORY SCHEDULE IS ENFORCED WITH sched_barrier(0), not source order:
// R8 vs R10 showed identical FETCH (223/226 MB) under different source orders
// -> the compiler pipelines next-chunk T/P loads across iterations, putting
// 32-48 random rows in flight per wave and thrashing the 4 MB per-XCD L2
// (R6's long scalar dep-chains accidentally prevented this: FETCH 80 MB).
// Barrier 1: after T->LDS store (P never overlaps T).
// Barrier 2: loop bottom (no cross-iteration load hoisting).
// ---------------------------------------------------------------------------
__global__ __launch_bounds__(1024, 4) void edge_kernel(
        const uint4* __restrict__ packE,
        const f16* __restrict__ P, const f16* __restrict__ T,
        const float* __restrict__ We1,
        const float* __restrict__ We2, const float* __restrict__ be2,
        const float* __restrict__ Wc,  const float* __restrict__ bc,
        float* __restrict__ h) {
    __shared__ f16 W2T[128 * 136];       // 34816 B
    __shared__ f16 WcT[128 * 136];       // 34816 B
    __shared__ f16 W1rT[128 * 40];       // 10240 B
    __shared__ f16 Uall[16 * 2176];      // 69632 B : per-wave 16x136 (T/u/ep) then mT
    __shared__ float sbe2[128], sbc[128];
    __shared__ int dstW[16][16];
    // total ~151.5 KB -> 1 block/CU, 16 waves

    int tid = threadIdx.x;
    stage_WT(We2, W2T, tid, 1024);
    stage_WT(Wc,  WcT, tid, 1024);
    for (int idx = tid; idx < 128 * 32; idx += 1024) {
        int n = idx >> 5, kr = idx & 31;
        W1rT[n * 40 + kr] = (kr < 30) ? (f16)We1[(128 + kr) * 128 + n] : (f16)0.0f;
    }
    if (tid < 128) { sbe2[tid] = be2[tid]; sbc[tid] = bc[tid]; }
    __syncthreads();    // weights ready; the ONLY block barrier

    int lane = tid & 63, wv = tid >> 6;
    f16* U = Uall + wv * 2176;
    int* dW = dstW[wv];
    int n16 = lane & 15, q = lane >> 4;
    const float invgap = 29.0f / 10.0f;
    int colA = lane, colB = lane + 64;
    int tsub = lane & 3, trow = lane >> 2;

    float sbcv[8];
    #pragma unroll
    for (int f = 0; f < 8; ++f) sbcv[f] = sbc[f * 16 + n16];

    // balanced stripe partition: 50000 chunks over 4096 waves (12 or 13 each)
    int wgid = blockIdx.x * 16 + wv;
    int extra = wgid < 848 ? wgid : 848;
    int c0 = wgid * 12 + extra;
    int c1 = c0 + 12 + (wgid < 848 ? 1 : 0);

    float carry0 = 0.0f, carry1 = 0.0f;
    int prev = -1;

    // prologue: pk for chunk c0
    uint4 pk = {0u, 0u, 0u, 0u};
    if (lane < 16) pk = packE[(size_t)c0 * 16 + lane];

    for (int ch = c0; ch < c1; ++ch) {
        bool hasNext = (ch + 1 < c1);
        // ---- distribute current records -----------------------------------
        int   ety  = __shfl((int)pk.y, trow);
        int   srcv = __shfl((int)pk.x, n16);
        float dcur = __shfl(__uint_as_float(pk.w), n16);
        if (lane < 16) dW[lane] = (int)pk.z;

        // ---- T loads, drained into LDS (phase A) --------------------------
        {
            const uint4* Tp = (const uint4*)(T + (size_t)ety * 128 + tsub * 32);
            uint4 tr0 = Tp[0], tr1 = Tp[1], tr2 = Tp[2], tr3 = Tp[3];
            uint4* ub = (uint4*)(U + trow * 136 + tsub * 32);
            ub[0] = tr0; ub[1] = tr1; ub[2] = tr2; ub[3] = tr3;
        }
        __builtin_amdgcn_sched_barrier(0);   // T drained before P issues

        // ---- NOW issue P loads (T no longer in flight) --------------------
        half8 pA0, pA1, pA2, pA3;
        {
            const f16* Pr = P + (size_t)srcv * 128 + q * 8;
            pA0 = *(const half8*)(Pr);
            pA1 = *(const half8*)(Pr + 32);
            pA2 = *(const half8*)(Pr + 64);
            pA3 = *(const half8*)(Pr + 96);
        }
        uint4 pkn = {0u, 0u, 0u, 0u};
        if (hasNext && lane < 16) pkn = packE[(size_t)(ch + 1) * 16 + lane];

        // ---- rbf in regs (VALU overlaps P latency) ------------------------
        half8 ar;
        #pragma unroll
        for (int j = 0; j < 8; ++j) {
            int k = q * 8 + j;
            float c = (float)k * (10.0f / 29.0f);
            float df = dcur - c;
            ar[j] = (f16)((k < 30) ? __expf(-df * df * invgap) : 0.0f);
        }

        // ---- B: u^T = relu(W1r^T @ rbf^T + T^T)  (all b64/b128) -----------
        #pragma unroll
        for (int f = 0; f < 8; ++f) {
            f16* up = U + n16 * 136 + f * 16 + q * 4;
            half4 tv = *(const half4*)up;
            floatx4 c4 = {(float)tv[0], (float)tv[1], (float)tv[2], (float)tv[3]};
            half8 aw = *(const half8*)(W1rT + (f * 16 + n16) * 40 + q * 8);
            c4 = __builtin_amdgcn_mfma_f32_16x16x32_f16(aw, ar, c4, 0, 0, 0);
            half4 uv;
            #pragma unroll
            for (int i = 0; i < 4; ++i) uv[i] = (f16)fmaxf(c4[i], 0.0f);
            *(half4*)up = uv;
        }

        // ---- C: ep^T = W2^T @ u^T + be2 -----------------------------------
        half8 a2[4];
        #pragma unroll
        for (int kk = 0; kk < 4; ++kk)
            a2[kk] = *(const half8*)(U + n16 * 136 + kk * 32 + q * 8);
        #pragma unroll
        for (int f = 0; f < 8; ++f) {
            floatx4 acc = *(const floatx4*)(sbe2 + f * 16 + q * 4);
            #pragma unroll
            for (int kk = 0; kk < 4; ++kk) {
                half8 aw = *(const half8*)(W2T + (f * 16 + n16) * 136 + kk * 32 + q * 8);
                acc = __builtin_amdgcn_mfma_f32_16x16x32_f16(aw, a2[kk], acc, 0, 0, 0);
            }
            half4 ev;
            #pragma unroll
            for (int i = 0; i < 4; ++i) ev[i] = (f16)acc[i];
            *(half4*)(U + n16 * 136 + f * 16 + q * 4) = ev;
        }

        // ---- E: m = tanh((P ⊙ ep) @ Wc + bc); write mT (b64, swizzled) ----
        {
            half8 e0 = *(const half8*)(U + n16 * 136 + 0 * 32 + q * 8);
            half8 e1 = *(const half8*)(U + n16 * 136 + 1 * 32 + q * 8);
            half8 e2 = *(const half8*)(U + n16 * 136 + 2 * 32 + q * 8);
            half8 e3 = *(const half8*)(U + n16 * 136 + 3 * 32 + q * 8);
            a2[0] = e0 * pA0; a2[1] = e1 * pA1; a2[2] = e2 * pA2; a2[3] = e3 * pA3;
        }
        #pragma unroll
        for (int f = 0; f < 8; ++f) {
            float bb = sbcv[f];
            floatx4 acc = {bb, bb, bb, bb};
            #pragma unroll
            for (int kk = 0; kk < 4; ++kk) {
                half8 b = *(const half8*)(WcT + (f * 16 + n16) * 136 + kk * 32 + q * 8);
                acc = __builtin_amdgcn_mfma_f32_16x16x32_f16(a2[kk], b, acc, 0, 0, 0);
            }
            int c = f * 16 + n16;
            half4 mv;
            #pragma unroll
            for (int i = 0; i < 4; ++i) mv[i] = (f16)fast_tanh(acc[i]);
            *(half4*)(U + mtAddr(c, q)) = mv;
        }

        // ---- F: per-col segment reduce with cross-chunk carry -------------
        {
            half4 va[4], vb[4];
            #pragma unroll
            for (int g2 = 0; g2 < 4; ++g2) {
                va[g2] = *(const half4*)(U + mtAddr(colA, g2));
                vb[g2] = *(const half4*)(U + mtAddr(colB, g2));
            }
            int dArr[16];
            *(int4*)(dArr)      = *(const int4*)(dW);
            *(int4*)(dArr + 4)  = *(const int4*)(dW + 4);
            *(int4*)(dArr + 8)  = *(const int4*)(dW + 8);
            *(int4*)(dArr + 12) = *(const int4*)(dW + 12);
            #pragma unroll
            for (int r = 0; r < 16; ++r) {
                int dd = dArr[r];
                float v0 = (float)va[r >> 2][r & 3];
                float v1 = (float)vb[r >> 2][r & 3];
                if (dd != prev) {   // wave-uniform branch
                    if (prev >= 0) {
                        unsafeAtomicAdd(&h[(size_t)prev * 128 + colA], carry0);
                        unsafeAtomicAdd(&h[(size_t)prev * 128 + colB], carry1);
                    }
                    prev = dd; carry0 = v0; carry1 = v1;
                } else { carry0 += v0; carry1 += v1; }
            }
        }
        pk = pkn;
        __builtin_amdgcn_sched_barrier(0);   // no cross-iteration load hoisting
    }
    if (prev >= 0) {
        unsafeAtomicAdd(&h[(size_t)prev * 128 + colA], carry0);
        unsafeAtomicAdd(&h[(size_t)prev * 128 + colB], carry1);
    }
}

// fused readout: hr = relu(h@Wr1+br1)·Wr2 + br2, out[gid] += hr  (per row)
__global__ __launch_bounds__(1024, 4) void readout_k(
        const float* __restrict__ X, int M,
        const float* __restrict__ W1, const float* __restrict__ b1,
        const float* __restrict__ Wr2, const float* __restrict__ br2,
        const int* __restrict__ gid, float* __restrict__ out) {
    __shared__ f16 W1T[128 * 136];
    __shared__ f16 xBuf[256 * 136];
    __shared__ float bias1[128];
    __shared__ float sWr2[128];
    int tid = threadIdx.x;

    stage_WT(W1, W1T, tid, 1024);
    if (tid < 128) { bias1[tid] = b1[tid]; sWr2[tid] = Wr2[tid]; }

    int r0 = blockIdx.x * 256;
    for (int it = 0; it < 8; ++it) {
        int row = it * 32 + (tid >> 5);
        int c4 = (tid & 31) * 4;
        int gr = r0 + row;
        floatx4 x = {0.0f, 0.0f, 0.0f, 0.0f};
        if (gr < M) x = *(const floatx4*)(X + (size_t)gr * 128 + c4);
        half4 xh;
        xh[0] = (f16)x[0]; xh[1] = (f16)x[1]; xh[2] = (f16)x[2]; xh[3] = (f16)x[3];
        *(half4*)(xBuf + row * 136 + c4) = xh;
    }
    __syncthreads();

    int lane = tid & 63, wv = tid >> 6;
    int R = wv * 16;
    int n16 = lane & 15, q = lane >> 4;

    half8 a[4];
    #pragma unroll
    for (int kk = 0; kk < 4; ++kk)
        a[kk] = *(const half8*)(xBuf + (R + n16) * 136 + kk * 32 + q * 8);

    floatx4 acc[8];
    #pragma unroll
    for (int f = 0; f < 8; ++f) {
        float bb = bias1[f * 16 + n16];
        acc[f] = (floatx4){bb, bb, bb, bb};
        #pragma unroll
        for (int kk = 0; kk < 4; ++kk) {
            half8 b = *(const half8*)(W1T + (f * 16 + n16) * 136 + kk * 32 + q * 8);
            acc[f] = __builtin_amdgcn_mfma_f32_16x16x32_f16(a[kk], b, acc[f], 0, 0, 0);
        }
    }

    float s[4];
    #pragma unroll
    for (int i = 0; i < 4; ++i) {
        float t = 0.0f;
        #pragma unroll
        for (int f = 0; f < 8; ++f)
            t += fmaxf(acc[f][i], 0.0f) * sWr2[f * 16 + n16];
        #pragma unroll
        for (int m = 1; m < 16; m <<= 1) t += __shfl_xor(t, m);
        s[i] = t;
    }

    if (n16 == 0) {
        float br2v = br2[0];
        float t = 0.0f; int g = -1;
        #pragma unroll
        for (int i = 0; i < 4; ++i) {
            int gr = r0 + R + q * 4 + i;
            if (gr < M) {
                int gi = gid[gr];
                float si = s[i] + br2v;
                if (gi == g) t += si;
                else { if (g >= 0) unsafeAtomicAdd(&out[g], t); g = gi; t = si; }
            }
        }
        if (g >= 0) unsafeAtomicAdd(&out[g], t);
    }
}

extern "C" void kernel_launch(void* const* d_in, const int* in_sizes, int n_in,
                              void* d_out, int out_size, void* d_ws, size_t ws_size,
                              hipStream_t stream) {
    (void)in_sizes; (void)n_in; (void)ws_size;
    const int*   node_types = (const int*)d_in[0];
    const int*   edge_types = (const int*)d_in[1];
    const int*   src        = (const int*)d_in[2];
    const int*   dst        = (const int*)d_in[3];
    const int*   graph_ids  = (const int*)d_in[4];
    const float* distances  = (const float*)d_in[5];
    const float* node_emb   = (const float*)d_in[7];
    const float* edge_emb   = (const float*)d_in[8];
    const float* Wn1 = (const float*)d_in[9];
    const float* bn1 = (const float*)d_in[10];
    const float* Wn2 = (const float*)d_in[11];
    const float* bn2 = (const float*)d_in[12];
    const float* We1 = (const float*)d_in[13];
    const float* be1 = (const float*)d_in[14];
    const float* We2 = (const float*)d_in[15];
    const float* be2 = (const float*)d_in[16];
    const float* Wc  = (const float*)d_in[17];
    const float* bc  = (const float*)d_in[18];
    const float* Wr1 = (const float*)d_in[19];
    const float* br1 = (const float*)d_in[20];
    const float* Wr2 = (const float*)d_in[21];
    const float* br2 = (const float*)d_in[22];

    char* w = (char*)d_ws;
    auto carve = [&](size_t bytes) { char* p = w; w += (bytes + 255) & ~(size_t)255; return p; };
    float* h        = (float*)carve((size_t)NNODES * 128 * 4);
    f16*   P        = (f16*)  carve((size_t)NNODES * 128 * 2);
    f16*   T        = (f16*)  carve((size_t)500 * 128 * 2);
    int*   rowStart = (int*)  carve((size_t)(NNODES + 1) * 4);
    int*   cnt      = (int*)  carve((size_t)NNODES * 4);
    int*   blockSum = (int*)  carve((size_t)64 * 4);
    uint4* packE    = (uint4*)carve((size_t)NEDGES * 16);

    float* out = (float*)d_out;
    const int NB1 = (NNODES + 1023) / 1024;   // 49

    init_k<<<(NNODES + 255) / 256, 256, 0, stream>>>(out, out_size, cnt);
    hist_k<<<NEDGES / 256, 256, 0, stream>>>(dst, cnt);
    scan1_k<<<NB1, 1024, 0, stream>>>(cnt, rowStart, blockSum);
    scan2_k<<<1, 64, 0, stream>>>(blockSum, NB1);
    scan3_k<<<NB1, 1024, 0, stream>>>(rowStart, blockSum, cnt);
    scatter_k<<<NEDGES / 256, 256, 0, stream>>>(src, edge_types, dst, distances,
                                                rowStart, cnt, packE);
    gather_h<<<(NNODES * 32 + 255) / 256, 256, 0, stream>>>(node_types, node_emb, h);

    for (int i = 0; i < 3; ++i) {
        mlp_kernel<2><<<(500 + 255) / 256, 1024, 0, stream>>>(
            edge_emb, 500, We1 + (size_t)i * 158 * 128, be1 + i * 128, nullptr, nullptr, T);
        mlp_kernel<0><<<(NNODES + 255) / 256, 1024, 0, stream>>>(
            h, NNODES, Wn1 + (size_t)i * 128 * 128, bn1 + i * 128,
            Wn2 + (size_t)i * 128 * 128, bn2 + i * 128, P);
        edge_kernel<<<256, 1024, 0, stream>>>(
            packE, P, T,
            We1 + (size_t)i * 158 * 128,
            We2 + (size_t)i * 128 * 128, be2 + i * 128,
            Wc + (size_t)i * 128 * 128, bc + i * 128, h);
    }

    readout_k<<<(NNODES + 255) / 256, 1024, 0, stream>>>(
        h, NNODES, Wr1, br1, Wr2, br2, graph_ids, out);
}